// Round 3
// baseline (474.478 us; speedup 1.0000x reference)
//
#include <hip/hip_runtime.h>

// B=8, C=128, H=W=128, HW=16384, positions total P=131072
typedef __attribute__((ext_vector_type(4))) float f32x4;
typedef __attribute__((ext_vector_type(2))) float f32x2;
typedef __attribute__((ext_vector_type(8))) short s16x8;
typedef __attribute__((ext_vector_type(4))) short s16x4;
typedef __bf16 bf16x8 __attribute__((ext_vector_type(8)));

__device__ __forceinline__ short f2bf(float f) {
  union { float f; unsigned u; } c; c.f = f;
  unsigned r = c.u + 0x7fffu + ((c.u >> 16) & 1u);
  return (short)(r >> 16);
}
__device__ __forceinline__ float bf2f(short s) {
  union { unsigned u; float f; } c; c.u = ((unsigned)(unsigned short)s) << 16;
  return c.f;
}

// ---------------------------------------------------------------------------
// K0: prep. W'[o][c] = lw[c]*W[o][c] (bf16); t1[o]=sum_c W'[o][c];
//     t2[o]=sum_c lb[c]*W[o][c] + conv_bias[o].   grid 3 (q,k,v), block 256.
// ---------------------------------------------------------------------------
__global__ void k0_prep(const float* __restrict__ qw1, const float* __restrict__ qb1,
                        const float* __restrict__ kvw1, const float* __restrict__ kvb1,
                        const float* __restrict__ ln1w, const float* __restrict__ ln1b,
                        const float* __restrict__ ln2w, const float* __restrict__ ln2b,
                        short* __restrict__ Wq, short* __restrict__ Wk, short* __restrict__ Wv,
                        float* __restrict__ T)  // [6][128]: t1q,t2q,t1k,t2k,t1v,t2v
{
  const int path = blockIdx.x;
  const int o = threadIdx.x >> 1, hf = threadIdx.x & 1;
  const float *W, *bias, *lw, *lb; short* Wo; float *t1, *t2;
  if (path == 0)      { W = qw1;            bias = qb1;       lw = ln2w; lb = ln2b; Wo = Wq; t1 = T;       t2 = T + 128; }
  else if (path == 1) { W = kvw1;           bias = kvb1;      lw = ln1w; lb = ln1b; Wo = Wk; t1 = T + 256; t2 = T + 384; }
  else                { W = kvw1 + 16384;   bias = kvb1+128;  lw = ln1w; lb = ln1b; Wo = Wv; t1 = T + 512; t2 = T + 640; }
  float s1 = 0.f, s2 = 0.f;
  for (int g = 0; g < 64; g++) {
    const int c = hf * 64 + g;
    const float w = W[o * 128 + c];
    const float wp = w * lw[c];
    s1 += wp; s2 += w * lb[c];
    Wo[o * 128 + c] = f2bf(wp);
  }
  s1 += __shfl_xor(s1, 1);
  s2 += __shfl_xor(s2, 1);
  if (hf == 0) { t1[o] = s1; t2[o] = s2 + bias[o]; }
}

// ---------------------------------------------------------------------------
// K1: merged LN+1x1conv GEMM, register-resident A, LDS OUTPUT staging.
//  grid 1024 = one block per 128-pos tile.  Per block:
//   pass q: lane-local A loads from cur (+LN stats via quad shfl), MFMA vs Wq,
//           epilogue -> ds_write Ot -> barrier -> full-line cooperative flush.
//   pass k: same from pre vs Wk.
//   pass v: REUSES pre A-frags + stats from registers, MFMA vs Wv.
//  pre is fetched from HBM exactly once; every global store instruction in
//  the flush covers complete 128B lines (16 lanes x 16B per plane) so write
//  amplification (round-1: 4x, round-2: 2x) is structurally impossible.
// ---------------------------------------------------------------------------
__device__ __forceinline__ void k1_load(const float* __restrict__ X, int mblk,
                                        int wv, int l16, int kof,
                                        bf16x8 (&A0)[4], bf16x8 (&A1)[4],
                                        float& mua, float& ra, float& mub, float& rb)
{
  const float* x0 = X + ((size_t)(mblk * 128 + wv * 32 + l16)) * 128;
  const float* x1 = x0 + 16 * 128;
  float s1a = 0.f, s2a = 0.f, s1b = 0.f, s2b = 0.f;
  union cvt8 { s16x8 s; bf16x8 b; };
#pragma unroll
  for (int ks = 0; ks < 4; ks++) {
    const int kb = ks * 32 + kof;
    const f32x4 p0 = *(const f32x4*)(x0 + kb);
    const f32x4 p1 = *(const f32x4*)(x0 + kb + 4);
    const f32x4 q0 = *(const f32x4*)(x1 + kb);
    const f32x4 q1 = *(const f32x4*)(x1 + kb + 4);
    cvt8 c0, c1;
#pragma unroll
    for (int j = 0; j < 4; j++) {
      s1a += p0[j] + p1[j]; s2a += p0[j] * p0[j] + p1[j] * p1[j];
      s1b += q0[j] + q1[j]; s2b += q0[j] * q0[j] + q1[j] * q1[j];
      c0.s[j] = f2bf(p0[j]); c0.s[4 + j] = f2bf(p1[j]);
      c1.s[j] = f2bf(q0[j]); c1.s[4 + j] = f2bf(q1[j]);
    }
    A0[ks] = c0.b; A1[ks] = c1.b;
  }
  s1a += __shfl_xor(s1a, 16); s1a += __shfl_xor(s1a, 32);
  s2a += __shfl_xor(s2a, 16); s2a += __shfl_xor(s2a, 32);
  s1b += __shfl_xor(s1b, 16); s1b += __shfl_xor(s1b, 32);
  s2b += __shfl_xor(s2b, 16); s2b += __shfl_xor(s2b, 32);
  mua = s1a * (1.f / 128.f);
  ra  = rsqrtf(s2a * (1.f / 128.f) - mua * mua + 1e-5f);
  mub = s1b * (1.f / 128.f);
  rb  = rsqrtf(s2b * (1.f / 128.f) - mub * mub + 1e-5f);
}

__device__ __forceinline__ void k1_pass(const bf16x8 (&A0)[4], const bf16x8 (&A1)[4],
                                        const short* __restrict__ Wp,
                                        const float* __restrict__ t1, const float* __restrict__ t2,
                                        float mua, float ra, float mub, float rb,
                                        short (&Ot)[128][132],
                                        int lane, int wv, int l16, int quad, int kof)
{
  f32x4 acc[2][8];
#pragma unroll
  for (int i = 0; i < 2; i++)
#pragma unroll
    for (int j = 0; j < 8; j++) acc[i][j] = (f32x4){0.f, 0.f, 0.f, 0.f};

#pragma unroll
  for (int ks = 0; ks < 4; ks++) {
    const int kb = ks * 32 + kof;
#pragma unroll
    for (int j = 0; j < 8; j++) {
      const bf16x8 bv = *(const bf16x8*)(Wp + (j * 16 + l16) * 128 + kb);
      acc[0][j] = __builtin_amdgcn_mfma_f32_16x16x32_bf16(A0[ks], bv, acc[0][j], 0, 0, 0);
      acc[1][j] = __builtin_amdgcn_mfma_f32_16x16x32_bf16(A1[ks], bv, acc[1][j], 0, 0, 0);
    }
  }
  float t1v[8], t2v[8];
#pragma unroll
  for (int j = 0; j < 8; j++) { const int o = j * 16 + l16; t1v[j] = t1[o]; t2v[j] = t2[o]; }

  const int sbase = (lane & 48) | (quad << 2);
#pragma unroll
  for (int i = 0; i < 2; i++) {
    float rs4[4], msr[4];
#pragma unroll
    for (int rg = 0; rg < 4; rg++) {
      const float mu = __shfl(i ? mub : mua, sbase + rg);
      const float rs = __shfl(i ? rb  : ra,  sbase + rg);
      rs4[rg] = rs; msr[rg] = mu * rs;
    }
    const int pr = wv * 32 + i * 16 + (quad << 2);
#pragma unroll
    for (int j = 0; j < 8; j++) {
      const int o = j * 16 + l16;
      s16x4 pk;
#pragma unroll
      for (int rg = 0; rg < 4; rg++) {
        const float y = rs4[rg] * acc[i][j][rg] - msr[rg] * t1v[j] + t2v[j];
        pk[rg] = f2bf(y);
      }
      *(s16x4*)&Ot[o][pr] = pk;
    }
  }
}

__device__ __forceinline__ void k1_flush(const short (&Ot)[128][132],
                                         short* __restrict__ Yout, int b, int pl0, int tid)
{
#pragma unroll
  for (int g = 0; g < 8; g++) {
    const int o = g * 16 + (tid >> 4);
    const int m = (tid & 15) * 8;
    const s16x4 lo = *(const s16x4*)&Ot[o][m];
    const s16x4 hi = *(const s16x4*)&Ot[o][m + 4];
    s16x8 v;
    v[0] = lo[0]; v[1] = lo[1]; v[2] = lo[2]; v[3] = lo[3];
    v[4] = hi[0]; v[5] = hi[1]; v[6] = hi[2]; v[7] = hi[3];
    *(s16x8*)(Yout + ((size_t)(b * 128 + o)) * 16384 + pl0 + m) = v;
  }
}

__global__ __launch_bounds__(256, 4)
void k1_ln_gemm(const float* __restrict__ cur, const float* __restrict__ pre,
                const short* __restrict__ Wq, const short* __restrict__ Wk,
                const short* __restrict__ Wv, const float* __restrict__ T,
                short* __restrict__ Yq, short* __restrict__ Yk, short* __restrict__ Yv)
{
  __shared__ __attribute__((aligned(16))) short Ot[128][132];
  const int tid = threadIdx.x, mblk = blockIdx.x;
  const int b = mblk >> 7;
  const int pl0 = (mblk & 127) * 128;
  const int wv = tid >> 6, lane = tid & 63, l16 = lane & 15, quad = lane >> 4, kof = quad * 8;

  bf16x8 A0[4], A1[4];
  float mua, ra, mub, rb;

  // ---- pass q: cur (LN2) ----
  k1_load(cur, mblk, wv, l16, kof, A0, A1, mua, ra, mub, rb);
  k1_pass(A0, A1, Wq, T, T + 128, mua, ra, mub, rb, Ot, lane, wv, l16, quad, kof);
  __syncthreads();
  k1_flush(Ot, Yq, b, pl0, tid);
  __syncthreads();

  // ---- pass k: pre (LN1) ----
  k1_load(pre, mblk, wv, l16, kof, A0, A1, mua, ra, mub, rb);
  k1_pass(A0, A1, Wk, T + 256, T + 384, mua, ra, mub, rb, Ot, lane, wv, l16, quad, kof);
  __syncthreads();
  k1_flush(Ot, Yk, b, pl0, tid);
  __syncthreads();

  // ---- pass v: reuse pre frags + stats from registers ----
  k1_pass(A0, A1, Wv, T + 512, T + 640, mua, ra, mub, rb, Ot, lane, wv, l16, quad, kof);
  __syncthreads();
  k1_flush(Ot, Yv, b, pl0, tid);
}

// ---------------------------------------------------------------------------
// K2: depthwise 3x3 on planar [c-plane][128x128] bf16, vectorized sliding
//  window along w. grid 3072 = path(3) x b(8) x c(128); block 256 =
//  (row 128) x (w-half 2). Also per-plane sum-of-squares for q,k norms.
// ---------------------------------------------------------------------------
__global__ __launch_bounds__(256, 4)
void k2_plane(const short* __restrict__ Yq, const short* __restrict__ Yk,
              const short* __restrict__ Yv,
              const float* __restrict__ qw2, const float* __restrict__ qb2,
              const float* __restrict__ kvw2, const float* __restrict__ kvb2,
              short* __restrict__ qo, short* __restrict__ ko, short* __restrict__ vo,
              float* __restrict__ nq, float* __restrict__ nk)
{
  __shared__ __attribute__((aligned(16))) short tile[130][144]; // inner at [h+1][w+8]
  __shared__ float red[256];
  const int tid = threadIdx.x, bx = blockIdx.x;
  const int path = bx >> 10, rem = bx & 1023;
  const int b = rem >> 7, c = rem & 127;
  const short* in; const float* w2p; float bsv; short* outp; float* np;
  if (path == 0)      { in = Yq; w2p = qw2 + c * 9;          bsv = qb2[c];        outp = qo; np = nq; }
  else if (path == 1) { in = Yk; w2p = kvw2 + c * 9;         bsv = kvb2[c];       outp = ko; np = nk; }
  else                { in = Yv; w2p = kvw2 + (128 + c) * 9; bsv = kvb2[128 + c]; outp = vo; np = nullptr; }

  const short* plane = in + ((size_t)(b * 128 + c)) * 16384;
#pragma unroll
  for (int g = 0; g < 8; g++) {
    const int e = (g * 256 + tid) * 8;
    *(s16x8*)&tile[(e >> 7) + 1][(e & 127) + 8] = *(const s16x8*)(plane + e);
  }
  const s16x8 z8 = (s16x8){0, 0, 0, 0, 0, 0, 0, 0};
  if (tid < 128) *(s16x8*)&tile[tid + 1][136] = z8;          // right halo
  if (tid < 36) { const int rr = (tid / 18) * 129, cc = (tid % 18) * 8; *(s16x8*)&tile[rr][cc] = z8; }
  __syncthreads();

  float wt[9];
#pragma unroll
  for (int j = 0; j < 9; j++) wt[j] = w2p[j];
  const int rr = tid >> 1, hfc = tid & 1;

  float A0[8], A1[8], A2[8];
  {
    const int ca = 8 + hfc * 64;
    const s16x8 a0 = *(const s16x8*)&tile[rr][ca];
    const s16x8 a1 = *(const s16x8*)&tile[rr + 1][ca];
    const s16x8 a2 = *(const s16x8*)&tile[rr + 2][ca];
#pragma unroll
    for (int x = 0; x < 8; x++) { A0[x] = bf2f(a0[x]); A1[x] = bf2f(a1[x]); A2[x] = bf2f(a2[x]); }
  }
  float p0, p1, p2;
  if (hfc) { p0 = bf2f(tile[rr][71]); p1 = bf2f(tile[rr + 1][71]); p2 = bf2f(tile[rr + 2][71]); }
  else { p0 = p1 = p2 = 0.f; }

  float ss = 0.f;
  short* oplane = outp + ((size_t)(b * 128 + c)) * 16384 + rr * 128 + hfc * 64;
#pragma unroll
  for (int g = 0; g < 8; g++) {
    const int cb = 16 + hfc * 64 + g * 8;
    const s16x8 b0 = *(const s16x8*)&tile[rr][cb];
    const s16x8 b1 = *(const s16x8*)&tile[rr + 1][cb];
    const s16x8 b2 = *(const s16x8*)&tile[rr + 2][cb];
    float B0[8], B1[8], B2[8];
#pragma unroll
    for (int x = 0; x < 8; x++) { B0[x] = bf2f(b0[x]); B1[x] = bf2f(b1[x]); B2[x] = bf2f(b2[x]); }
    s16x8 ov;
#pragma unroll
    for (int x = 0; x < 8; x++) {
      const float l0 = x ? A0[x - 1] : p0, l1 = x ? A1[x - 1] : p1, l2 = x ? A2[x - 1] : p2;
      const float r0 = (x < 7) ? A0[x + 1] : B0[0];
      const float r1 = (x < 7) ? A1[x + 1] : B1[0];
      const float r2 = (x < 7) ? A2[x + 1] : B2[0];
      float s = bsv;
      s += wt[0] * l0 + wt[1] * A0[x] + wt[2] * r0;
      s += wt[3] * l1 + wt[4] * A1[x] + wt[5] * r1;
      s += wt[6] * l2 + wt[7] * A2[x] + wt[8] * r2;
      ov[x] = f2bf(s); ss += s * s;
    }
    *(s16x8*)(oplane + g * 8) = ov;
    p0 = A0[7]; p1 = A1[7]; p2 = A2[7];
#pragma unroll
    for (int x = 0; x < 8; x++) { A0[x] = B0[x]; A1[x] = B1[x]; A2[x] = B2[x]; }
  }
  red[tid] = ss;
  __syncthreads();
  if (tid < 64) {
    float t = red[tid] + red[tid + 64] + red[tid + 128] + red[tid + 192];
#pragma unroll
    for (int m = 32; m >= 1; m >>= 1) t += __shfl_xor(t, m);
    if (tid == 0 && np) np[b * 128 + c] = t;
  }
}

// ---------------------------------------------------------------------------
// K3: Gram partials from planar q,k — MFMA frags DIRECT from global.
//  grid 512 = b(8) x 64 n-splits of 256; block 256 computes full 128x128.
// ---------------------------------------------------------------------------
__global__ __launch_bounds__(256, 2)
void k3_gram(const short* __restrict__ qo, const short* __restrict__ ko,
             float* __restrict__ Gp)
{
  const int tid = threadIdx.x, bx = blockIdx.x;
  const int b = bx >> 6, sp = bx & 63;
  const int wv = tid >> 6, lane = tid & 63, l16 = lane & 15, quad = lane >> 4, kof = quad * 8;
  f32x4 acc[2][8];
#pragma unroll
  for (int i = 0; i < 2; i++)
#pragma unroll
    for (int j = 0; j < 8; j++) acc[i][j] = (f32x4){0.f, 0.f, 0.f, 0.f};

  const short* qb = qo + (size_t)b * 128 * 16384 + sp * 256 + kof;
  const short* kb = ko + (size_t)b * 128 * 16384 + sp * 256 + kof;
#pragma unroll
  for (int ks = 0; ks < 8; ks++) {
    const int n0 = ks * 32;
    const bf16x8 a0 = *(const bf16x8*)(qb + (size_t)(wv * 32 + l16) * 16384 + n0);
    const bf16x8 a1 = *(const bf16x8*)(qb + (size_t)(wv * 32 + 16 + l16) * 16384 + n0);
#pragma unroll
    for (int j = 0; j < 8; j++) {
      const bf16x8 bv = *(const bf16x8*)(kb + (size_t)(j * 16 + l16) * 16384 + n0);
      acc[0][j] = __builtin_amdgcn_mfma_f32_16x16x32_bf16(a0, bv, acc[0][j], 0, 0, 0);
      acc[1][j] = __builtin_amdgcn_mfma_f32_16x16x32_bf16(a1, bv, acc[1][j], 0, 0, 0);
    }
  }
  float* gp = Gp + ((size_t)(sp * 8 + b)) * 16384;
#pragma unroll
  for (int i = 0; i < 2; i++)
#pragma unroll
    for (int j = 0; j < 8; j++)
#pragma unroll
      for (int rg = 0; rg < 4; rg++)
        gp[(wv * 32 + i * 16 + quad * 4 + rg) * 128 + j * 16 + l16] = acc[i][j][rg];
}

// ---------------------------------------------------------------------------
// K4a: reduce 64 partials, l2-norm rescale, softmax over d. grid 128.
// ---------------------------------------------------------------------------
__global__ void k4a_softmax(const float* __restrict__ Gp,
                            const float* __restrict__ nq, const float* __restrict__ nk,
                            float* __restrict__ att)
{
  const int tid = threadIdx.x;
  const int b = blockIdx.x >> 4, cb = (blockIdx.x & 15) * 8;
  const int r = tid >> 5, dsi = tid & 31;
  const int c = cb + r, d0 = dsi * 4;
  f32x4 a = (f32x4){0.f, 0.f, 0.f, 0.f};
  for (int ks = 0; ks < 64; ks++)
    a += *(const f32x4*)(Gp + ((size_t)(ks * 8 + b)) * 16384 + c * 128 + d0);
  const float qn = fmaxf(sqrtf(nq[b * 128 + c]), 1e-12f);
  f32x4 sc;
#pragma unroll
  for (int j = 0; j < 4; j++) {
    const float kn = fmaxf(sqrtf(nk[b * 128 + d0 + j]), 1e-12f);
    sc[j] = a[j] / (qn * kn);
  }
  float mx = fmaxf(fmaxf(sc[0], sc[1]), fmaxf(sc[2], sc[3]));
#pragma unroll
  for (int m = 16; m >= 1; m >>= 1) mx = fmaxf(mx, __shfl_xor(mx, m));
  f32x4 e; float sum = 0.f;
#pragma unroll
  for (int j = 0; j < 4; j++) { e[j] = __expf(sc[j] - mx); sum += e[j]; }
#pragma unroll
  for (int m = 16; m >= 1; m >>= 1) sum += __shfl_xor(sum, m);
  const float inv = 1.f / sum;
  f32x4 o;
#pragma unroll
  for (int j = 0; j < 4; j++) o[j] = e[j] * inv;
  *(f32x4*)(att + (size_t)b * 16384 + c * 128 + d0) = o;
}

// ---------------------------------------------------------------------------
// K4b: M[b][o][d] = sum_c out_w[o][c]*att[b][c][d], bf16.
//  grid 128 = b(8) x 16 d-groups of 8; att tile staged in LDS.
// ---------------------------------------------------------------------------
__global__ void k4b_mw(const float* __restrict__ att, const float* __restrict__ outw,
                       short* __restrict__ Mb)
{
  __shared__ float at[128][8];
  const int tid = threadIdx.x, bx = blockIdx.x;
  const int b = bx >> 4, d0 = (bx & 15) * 8;
  {
    const int cc = tid >> 1, q = tid & 1;
    *(f32x4*)&at[cc][q * 4] = *(const f32x4*)(att + (size_t)b * 16384 + cc * 128 + d0 + q * 4);
  }
  __syncthreads();
  const int o = tid & 127, dq = (tid >> 7) * 4;
  f32x4 acc = (f32x4){0.f, 0.f, 0.f, 0.f};
  const float* wr = outw + o * 128;
  for (int cc = 0; cc < 128; cc++) {
    const float w = wr[cc];
    const f32x4 a = *(const f32x4*)&at[cc][dq];
    acc += w * a;
  }
  s16x4 pk;
#pragma unroll
  for (int rg = 0; rg < 4; rg++) pk[rg] = f2bf(acc[rg]);
  *(s16x4*)(Mb + ((size_t)(b * 128 + o)) * 128 + d0 + dq) = pk;
}

// ---------------------------------------------------------------------------
// K5: out[b][n][o] = sum_d M[o][d]*v[d][n] + out_b[o] + cur[b][n][o].
//  v planar -> LDS transpose staging; D rows=o cols=pos; f32x4 stores.
//  grid 1024 = b(8) x 128 pos-chunks.
// ---------------------------------------------------------------------------
__global__ __launch_bounds__(256, 3)
void k5_out(const short* __restrict__ Mb, const short* __restrict__ vp,
            const float* __restrict__ outb, const float* __restrict__ cur,
            float* __restrict__ out)
{
  __shared__ __attribute__((aligned(16))) short Vt[128][136];
  const int tid = threadIdx.x;
  const int b = blockIdx.x >> 7, nb = (blockIdx.x & 127) * 128;
  {
    const int d = tid >> 1, hf = tid & 1;
    const short* src = vp + ((size_t)(b * 128 + d)) * 16384 + nb + hf * 64;
#pragma unroll
    for (int g = 0; g < 8; g++) {
      const s16x8 v = *(const s16x8*)(src + g * 8);
#pragma unroll
      for (int x = 0; x < 8; x++) Vt[hf * 64 + g * 8 + x][d] = v[x];
    }
  }
  __syncthreads();
  const int wv = tid >> 6, lane = tid & 63, l16 = lane & 15, quad = lane >> 4, kof = quad * 8;
  f32x4 acc[2][8];
#pragma unroll
  for (int i = 0; i < 2; i++)
#pragma unroll
    for (int j = 0; j < 8; j++) acc[i][j] = (f32x4){0.f, 0.f, 0.f, 0.f};

  const short* m0 = Mb + ((size_t)(b * 128 + wv * 32 + l16)) * 128;
  const short* m1 = m0 + 16 * 128;
#pragma unroll
  for (int ks = 0; ks < 4; ks++) {
    const int kb = ks * 32 + kof;
    const bf16x8 a0 = *(const bf16x8*)(m0 + kb);
    const bf16x8 a1 = *(const bf16x8*)(m1 + kb);
#pragma unroll
    for (int j = 0; j < 8; j++) {
      const bf16x8 bv = *(const bf16x8*)&Vt[j * 16 + l16][kb];
      acc[0][j] = __builtin_amdgcn_mfma_f32_16x16x32_bf16(a0, bv, acc[0][j], 0, 0, 0);
      acc[1][j] = __builtin_amdgcn_mfma_f32_16x16x32_bf16(a1, bv, acc[1][j], 0, 0, 0);
    }
  }
#pragma unroll
  for (int i = 0; i < 2; i++) {
    const int o0 = wv * 32 + i * 16 + quad * 4;
    const f32x4 bias = *(const f32x4*)(outb + o0);
#pragma unroll
    for (int j = 0; j < 8; j++) {
      const int pos = nb + j * 16 + l16;
      const size_t idx = ((size_t)(b * 16384 + pos)) * 128 + o0;
      const f32x4 cv = *(const f32x4*)(cur + idx);
      f32x4 rr;
#pragma unroll
      for (int rg = 0; rg < 4; rg++) rr[rg] = acc[i][j][rg] + bias[rg] + cv[rg];
      *(f32x4*)(out + idx) = rr;
    }
  }
}

// ---------------------------------------------------------------------------
extern "C" void kernel_launch(void* const* d_in, const int* in_sizes, int n_in,
                              void* d_out, int out_size, void* d_ws, size_t ws_size,
                              hipStream_t stream) {
  const float* pre  = (const float*)d_in[0];
  const float* cur  = (const float*)d_in[1];
  const float* ln1w = (const float*)d_in[2];
  const float* ln1b = (const float*)d_in[3];
  const float* ln2w = (const float*)d_in[4];
  const float* ln2b = (const float*)d_in[5];
  const float* qw1  = (const float*)d_in[6];
  const float* qb1  = (const float*)d_in[7];
  const float* qw2  = (const float*)d_in[8];
  const float* qb2  = (const float*)d_in[9];
  const float* kvw1 = (const float*)d_in[10];
  const float* kvb1 = (const float*)d_in[11];
  const float* kvw2 = (const float*)d_in[12];
  const float* kvb2 = (const float*)d_in[13];
  const float* outw = (const float*)d_in[14];
  const float* outb = (const float*)d_in[15];

  char* ws = (char*)d_ws;
  short* Yq  = (short*)(ws);                 // 32M planar [b*c][n]
  short* Yk  = (short*)(ws + 33554432);      // 32M planar
  short* Yv  = (short*)(ws + 67108864);      // 32M planar
  short* qo  = (short*)(ws + 100663296);     // 32M planar
  short* ko  = (short*)(ws + 134217728);     // 32M planar
  short* vo  = (short*)(ws + 167772160);     // 32M planar
  float* Gp  = (float*)(ws);                 // 32M, aliases Yq (dead after k2)
  float* att = (float*)(ws + 33554432);      // 512K, aliases Yk
  short* Mb  = (short*)(ws + 34078720);      // 256K, aliases Yk
  char*  sm  = ws + 201326592;
  short* Wq  = (short*)(sm);                 // 32K
  short* Wk  = (short*)(sm + 32768);
  short* Wv  = (short*)(sm + 65536);
  float* T   = (float*)(sm + 98304);         // 3K
  float* nq  = (float*)(sm + 102400);        // 4K
  float* nk  = (float*)(sm + 106496);        // 4K

  hipLaunchKernelGGL(k0_prep, dim3(3), dim3(256), 0, stream,
                     qw1, qb1, kvw1, kvb1, ln1w, ln1b, ln2w, ln2b, Wq, Wk, Wv, T);
  hipLaunchKernelGGL(k1_ln_gemm, dim3(1024), dim3(256), 0, stream,
                     cur, pre, Wq, Wk, Wv, T, Yq, Yk, Yv);
  hipLaunchKernelGGL(k2_plane, dim3(3072), dim3(256), 0, stream,
                     Yq, Yk, Yv, qw2, qb2, kvw2, kvb2, qo, ko, vo, nq, nk);
  hipLaunchKernelGGL(k3_gram, dim3(512), dim3(256), 0, stream, qo, ko, Gp);
  hipLaunchKernelGGL(k4a_softmax, dim3(128), dim3(256), 0, stream, Gp, nq, nk, att);
  hipLaunchKernelGGL(k4b_mw, dim3(128), dim3(256), 0, stream, att, outw, Mb);
  hipLaunchKernelGGL(k5_out, dim3(1024), dim3(256), 0, stream, Mb, vo, outb, cur, (float*)d_out);
}

// Round 4
// 426.284 us; speedup vs baseline: 1.1131x; 1.1131x over previous
//
#include <hip/hip_runtime.h>

// B=8, C=128, H=W=128, HW=16384, positions total P=131072
typedef __attribute__((ext_vector_type(4))) float f32x4;
typedef __attribute__((ext_vector_type(2))) float f32x2;
typedef __attribute__((ext_vector_type(8))) short s16x8;
typedef __attribute__((ext_vector_type(4))) short s16x4;
typedef __bf16 bf16x8 __attribute__((ext_vector_type(8)));

__device__ __forceinline__ short f2bf(float f) {
  union { float f; unsigned u; } c; c.f = f;
  unsigned r = c.u + 0x7fffu + ((c.u >> 16) & 1u);
  return (short)(r >> 16);
}
__device__ __forceinline__ float bf2f(short s) {
  union { unsigned u; float f; } c; c.u = ((unsigned)(unsigned short)s) << 16;
  return c.f;
}

// ---------------------------------------------------------------------------
// K0: prep. W'[o][c] = lw[c]*W[o][c] (bf16); t1[o]=sum_c W'[o][c];
//     t2[o]=sum_c lb[c]*W[o][c] + conv_bias[o].   grid 3 (q,k,v), block 256.
// ---------------------------------------------------------------------------
__global__ void k0_prep(const float* __restrict__ qw1, const float* __restrict__ qb1,
                        const float* __restrict__ kvw1, const float* __restrict__ kvb1,
                        const float* __restrict__ ln1w, const float* __restrict__ ln1b,
                        const float* __restrict__ ln2w, const float* __restrict__ ln2b,
                        short* __restrict__ Wq, short* __restrict__ Wk, short* __restrict__ Wv,
                        float* __restrict__ T)  // [6][128]: t1q,t2q,t1k,t2k,t1v,t2v
{
  const int path = blockIdx.x;
  const int o = threadIdx.x >> 1, hf = threadIdx.x & 1;
  const float *W, *bias, *lw, *lb; short* Wo; float *t1, *t2;
  if (path == 0)      { W = qw1;            bias = qb1;       lw = ln2w; lb = ln2b; Wo = Wq; t1 = T;       t2 = T + 128; }
  else if (path == 1) { W = kvw1;           bias = kvb1;      lw = ln1w; lb = ln1b; Wo = Wk; t1 = T + 256; t2 = T + 384; }
  else                { W = kvw1 + 16384;   bias = kvb1+128;  lw = ln1w; lb = ln1b; Wo = Wv; t1 = T + 512; t2 = T + 640; }
  float s1 = 0.f, s2 = 0.f;
  for (int g = 0; g < 64; g++) {
    const int c = hf * 64 + g;
    const float w = W[o * 128 + c];
    const float wp = w * lw[c];
    s1 += wp; s2 += w * lb[c];
    Wo[o * 128 + c] = f2bf(wp);
  }
  s1 += __shfl_xor(s1, 1);
  s2 += __shfl_xor(s2, 1);
  if (hf == 0) { t1[o] = s1; t2[o] = s2 + bias[o]; }
}

// ---------------------------------------------------------------------------
// K1: LN+1x1conv GEMM, path-split grid (clean-traffic round-0 structure:
//  concurrent write-set per XCD = 3 blk/CU x 32 CU x 32 KB = 3 MiB < 4 MiB L2,
//  so scatter stores coalesce in L2 -> no write amplification), plus a
//  2-tile software pipeline: grid 1536 = path(3) x 512 tile-pairs; tile1's
//  global f32 loads are issued into registers BEFORE tile0's MFMA+epilogue
//  so every block keeps ~64 KB of loads in flight during compute phases.
//  All 3 paths identical: D rows = pos, cols = o, planar store Y[c][n].
// ---------------------------------------------------------------------------
__device__ __forceinline__ void k1_loadR(const float* __restrict__ src, f32x4 (&PR)[16])
{
#pragma unroll
  for (int g = 0; g < 8; g++) {
    PR[2 * g]     = *(const f32x4*)(src + g * 8);
    PR[2 * g + 1] = *(const f32x4*)(src + g * 8 + 4);
  }
}

__device__ __forceinline__ void k1_stageW(const f32x4 (&PR)[16], int tid,
                                          short (&At)[128][136], f32x2 (&rowstat)[128])
{
  const int r = tid >> 1, hf = tid & 1;
  float s1 = 0.f, s2 = 0.f;
#pragma unroll
  for (int g = 0; g < 8; g++) {
    const f32x4 v0 = PR[2 * g];
    const f32x4 v1 = PR[2 * g + 1];
    s16x8 o;
#pragma unroll
    for (int j = 0; j < 4; j++) {
      s1 += v0[j] + v1[j]; s2 += v0[j] * v0[j] + v1[j] * v1[j];
      o[j] = f2bf(v0[j]); o[4 + j] = f2bf(v1[j]);
    }
    *(s16x8*)&At[r][hf * 64 + g * 8] = o;
  }
  s1 += __shfl_xor(s1, 1);
  s2 += __shfl_xor(s2, 1);
  if (hf == 0) {
    const float mu = s1 * (1.f / 128.f);
    const float var = s2 * (1.f / 128.f) - mu * mu;
    rowstat[r] = (f32x2){mu, rsqrtf(var + 1e-5f)};
  }
}

__device__ __forceinline__ void k1_gemm_epi(const short (&At)[128][136],
                                            const f32x2 (&rowstat)[128],
                                            const short* __restrict__ Wp,
                                            const float* __restrict__ t1,
                                            const float* __restrict__ t2,
                                            short* __restrict__ Yout,
                                            int b, int pl0,
                                            int wv, int l16, int quad, int kof)
{
  f32x4 acc[2][8];
#pragma unroll
  for (int i = 0; i < 2; i++)
#pragma unroll
    for (int j = 0; j < 8; j++) acc[i][j] = (f32x4){0.f, 0.f, 0.f, 0.f};

#pragma unroll
  for (int ks = 0; ks < 4; ks++) {
    const int kb = ks * 32 + kof;
    const bf16x8 a0 = *(const bf16x8*)&At[wv * 32 + l16][kb];
    const bf16x8 a1 = *(const bf16x8*)&At[wv * 32 + 16 + l16][kb];
#pragma unroll
    for (int j = 0; j < 8; j++) {
      const bf16x8 bv = *(const bf16x8*)(Wp + (j * 16 + l16) * 128 + kb);
      acc[0][j] = __builtin_amdgcn_mfma_f32_16x16x32_bf16(a0, bv, acc[0][j], 0, 0, 0);
      acc[1][j] = __builtin_amdgcn_mfma_f32_16x16x32_bf16(a1, bv, acc[1][j], 0, 0, 0);
    }
  }
  float t1v[8], t2v[8];
#pragma unroll
  for (int j = 0; j < 8; j++) { const int o = j * 16 + l16; t1v[j] = t1[o]; t2v[j] = t2[o]; }
#pragma unroll
  for (int i = 0; i < 2; i++) {
    const int pr = wv * 32 + i * 16 + quad * 4;
    f32x2 st[4];
#pragma unroll
    for (int rg = 0; rg < 4; rg++) st[rg] = rowstat[pr + rg];
#pragma unroll
    for (int j = 0; j < 8; j++) {
      const int o = j * 16 + l16;
      s16x4 pk;
#pragma unroll
      for (int rg = 0; rg < 4; rg++) {
        const float y = st[rg].y * acc[i][j][rg] - st[rg].x * st[rg].y * t1v[j] + t2v[j];
        pk[rg] = f2bf(y);
      }
      *(s16x4*)(Yout + ((size_t)(b * 128 + o)) * 16384 + pl0 + pr) = pk;
    }
  }
}

__global__ __launch_bounds__(256, 3)
void k1_ln_gemm(const float* __restrict__ cur, const float* __restrict__ pre,
                const short* __restrict__ Wq, const short* __restrict__ Wk,
                const short* __restrict__ Wv, const float* __restrict__ T,
                short* __restrict__ Yq, short* __restrict__ Yk, short* __restrict__ Yv)
{
  __shared__ __attribute__((aligned(16))) short At[128][136];
  __shared__ f32x2 rowstat[128];
  const int tid = threadIdx.x, bx = blockIdx.x;
  const int path = bx >> 9;
  const int m0 = (bx & 511) * 2;                 // tiles m0, m0+1
  const float* X = (path == 0) ? cur : pre;
  const short* Wp = (path == 0) ? Wq : (path == 1) ? Wk : Wv;
  short* Yout = (path == 0) ? Yq : (path == 1) ? Yk : Yv;
  const float* t1 = T + path * 256;
  const float* t2 = t1 + 128;
  const int wv = tid >> 6, lane = tid & 63, l16 = lane & 15, quad = lane >> 4, kof = quad * 8;
  const int r = tid >> 1, hf = tid & 1;
  const float* src0 = X + ((size_t)(m0 * 128 + r)) * 128 + hf * 64;

  f32x4 PR[16];
  // tile 0: load -> stage
  k1_loadR(src0, PR);
  k1_stageW(PR, tid, At, rowstat);
  __syncthreads();
  // issue tile 1's loads, then compute tile 0 while they fly
  k1_loadR(src0 + 16384, PR);
  k1_gemm_epi(At, rowstat, Wp, t1, t2, Yout, m0 >> 7, (m0 & 127) * 128,
              wv, l16, quad, kof);
  __syncthreads();            // tile-0 LDS reads done before restage
  k1_stageW(PR, tid, At, rowstat);
  __syncthreads();
  k1_gemm_epi(At, rowstat, Wp, t1, t2, Yout, (m0 + 1) >> 7, ((m0 + 1) & 127) * 128,
              wv, l16, quad, kof);
}

// ---------------------------------------------------------------------------
// K2: depthwise 3x3 on planar [c-plane][128x128] bf16, vectorized sliding
//  window along w. grid 3072 = path(3) x b(8) x c(128); block 256 =
//  (row 128) x (w-half 2). Also per-plane sum-of-squares for q,k norms.
// ---------------------------------------------------------------------------
__global__ __launch_bounds__(256, 4)
void k2_plane(const short* __restrict__ Yq, const short* __restrict__ Yk,
              const short* __restrict__ Yv,
              const float* __restrict__ qw2, const float* __restrict__ qb2,
              const float* __restrict__ kvw2, const float* __restrict__ kvb2,
              short* __restrict__ qo, short* __restrict__ ko, short* __restrict__ vo,
              float* __restrict__ nq, float* __restrict__ nk)
{
  __shared__ __attribute__((aligned(16))) short tile[130][144]; // inner at [h+1][w+8]
  __shared__ float red[256];
  const int tid = threadIdx.x, bx = blockIdx.x;
  const int path = bx >> 10, rem = bx & 1023;
  const int b = rem >> 7, c = rem & 127;
  const short* in; const float* w2p; float bsv; short* outp; float* np;
  if (path == 0)      { in = Yq; w2p = qw2 + c * 9;          bsv = qb2[c];        outp = qo; np = nq; }
  else if (path == 1) { in = Yk; w2p = kvw2 + c * 9;         bsv = kvb2[c];       outp = ko; np = nk; }
  else                { in = Yv; w2p = kvw2 + (128 + c) * 9; bsv = kvb2[128 + c]; outp = vo; np = nullptr; }

  const short* plane = in + ((size_t)(b * 128 + c)) * 16384;
#pragma unroll
  for (int g = 0; g < 8; g++) {
    const int e = (g * 256 + tid) * 8;
    *(s16x8*)&tile[(e >> 7) + 1][(e & 127) + 8] = *(const s16x8*)(plane + e);
  }
  const s16x8 z8 = (s16x8){0, 0, 0, 0, 0, 0, 0, 0};
  if (tid < 128) *(s16x8*)&tile[tid + 1][136] = z8;          // right halo
  if (tid < 36) { const int rr = (tid / 18) * 129, cc = (tid % 18) * 8; *(s16x8*)&tile[rr][cc] = z8; }
  __syncthreads();

  float wt[9];
#pragma unroll
  for (int j = 0; j < 9; j++) wt[j] = w2p[j];
  const int rr = tid >> 1, hfc = tid & 1;

  float A0[8], A1[8], A2[8];
  {
    const int ca = 8 + hfc * 64;
    const s16x8 a0 = *(const s16x8*)&tile[rr][ca];
    const s16x8 a1 = *(const s16x8*)&tile[rr + 1][ca];
    const s16x8 a2 = *(const s16x8*)&tile[rr + 2][ca];
#pragma unroll
    for (int x = 0; x < 8; x++) { A0[x] = bf2f(a0[x]); A1[x] = bf2f(a1[x]); A2[x] = bf2f(a2[x]); }
  }
  float p0, p1, p2;
  if (hfc) { p0 = bf2f(tile[rr][71]); p1 = bf2f(tile[rr + 1][71]); p2 = bf2f(tile[rr + 2][71]); }
  else { p0 = p1 = p2 = 0.f; }

  float ss = 0.f;
  short* oplane = outp + ((size_t)(b * 128 + c)) * 16384 + rr * 128 + hfc * 64;
#pragma unroll
  for (int g = 0; g < 8; g++) {
    const int cb = 16 + hfc * 64 + g * 8;
    const s16x8 b0 = *(const s16x8*)&tile[rr][cb];
    const s16x8 b1 = *(const s16x8*)&tile[rr + 1][cb];
    const s16x8 b2 = *(const s16x8*)&tile[rr + 2][cb];
    float B0[8], B1[8], B2[8];
#pragma unroll
    for (int x = 0; x < 8; x++) { B0[x] = bf2f(b0[x]); B1[x] = bf2f(b1[x]); B2[x] = bf2f(b2[x]); }
    s16x8 ov;
#pragma unroll
    for (int x = 0; x < 8; x++) {
      const float l0 = x ? A0[x - 1] : p0, l1 = x ? A1[x - 1] : p1, l2 = x ? A2[x - 1] : p2;
      const float r0 = (x < 7) ? A0[x + 1] : B0[0];
      const float r1 = (x < 7) ? A1[x + 1] : B1[0];
      const float r2 = (x < 7) ? A2[x + 1] : B2[0];
      float s = bsv;
      s += wt[0] * l0 + wt[1] * A0[x] + wt[2] * r0;
      s += wt[3] * l1 + wt[4] * A1[x] + wt[5] * r1;
      s += wt[6] * l2 + wt[7] * A2[x] + wt[8] * r2;
      ov[x] = f2bf(s); ss += s * s;
    }
    *(s16x8*)(oplane + g * 8) = ov;
    p0 = A0[7]; p1 = A1[7]; p2 = A2[7];
#pragma unroll
    for (int x = 0; x < 8; x++) { A0[x] = B0[x]; A1[x] = B1[x]; A2[x] = B2[x]; }
  }
  red[tid] = ss;
  __syncthreads();
  if (tid < 64) {
    float t = red[tid] + red[tid + 64] + red[tid + 128] + red[tid + 192];
#pragma unroll
    for (int m = 32; m >= 1; m >>= 1) t += __shfl_xor(t, m);
    if (tid == 0 && np) np[b * 128 + c] = t;
  }
}

// ---------------------------------------------------------------------------
// K3: Gram partials from planar q,k — MFMA frags DIRECT from global.
//  grid 512 = b(8) x 64 n-splits of 256; block 256 computes full 128x128.
// ---------------------------------------------------------------------------
__global__ __launch_bounds__(256, 2)
void k3_gram(const short* __restrict__ qo, const short* __restrict__ ko,
             float* __restrict__ Gp)
{
  const int tid = threadIdx.x, bx = blockIdx.x;
  const int b = bx >> 6, sp = bx & 63;
  const int wv = tid >> 6, lane = tid & 63, l16 = lane & 15, quad = lane >> 4, kof = quad * 8;
  f32x4 acc[2][8];
#pragma unroll
  for (int i = 0; i < 2; i++)
#pragma unroll
    for (int j = 0; j < 8; j++) acc[i][j] = (f32x4){0.f, 0.f, 0.f, 0.f};

  const short* qb = qo + (size_t)b * 128 * 16384 + sp * 256 + kof;
  const short* kb = ko + (size_t)b * 128 * 16384 + sp * 256 + kof;
#pragma unroll
  for (int ks = 0; ks < 8; ks++) {
    const int n0 = ks * 32;
    const bf16x8 a0 = *(const bf16x8*)(qb + (size_t)(wv * 32 + l16) * 16384 + n0);
    const bf16x8 a1 = *(const bf16x8*)(qb + (size_t)(wv * 32 + 16 + l16) * 16384 + n0);
#pragma unroll
    for (int j = 0; j < 8; j++) {
      const bf16x8 bv = *(const bf16x8*)(kb + (size_t)(j * 16 + l16) * 16384 + n0);
      acc[0][j] = __builtin_amdgcn_mfma_f32_16x16x32_bf16(a0, bv, acc[0][j], 0, 0, 0);
      acc[1][j] = __builtin_amdgcn_mfma_f32_16x16x32_bf16(a1, bv, acc[1][j], 0, 0, 0);
    }
  }
  float* gp = Gp + ((size_t)(sp * 8 + b)) * 16384;
#pragma unroll
  for (int i = 0; i < 2; i++)
#pragma unroll
    for (int j = 0; j < 8; j++)
#pragma unroll
      for (int rg = 0; rg < 4; rg++)
        gp[(wv * 32 + i * 16 + quad * 4 + rg) * 128 + j * 16 + l16] = acc[i][j][rg];
}

// ---------------------------------------------------------------------------
// K4a: reduce 64 partials, l2-norm rescale, softmax over d.
//  One WAVE per attention row (b,c): lane d0 = lane*2, full 64-lane reduce.
//  grid 256 = b(8) x 32 c-quads; block 256 = 4 waves = 4 rows.
// ---------------------------------------------------------------------------
__global__ void k4a_softmax(const float* __restrict__ Gp,
                            const float* __restrict__ nq, const float* __restrict__ nk,
                            float* __restrict__ att)
{
  const int tid = threadIdx.x;
  const int b = blockIdx.x >> 5;
  const int c = (blockIdx.x & 31) * 4 + (tid >> 6);
  const int lane = tid & 63;
  const int d0 = lane * 2;
  f32x2 a = (f32x2){0.f, 0.f};
  for (int ks = 0; ks < 64; ks++)
    a += *(const f32x2*)(Gp + ((size_t)(ks * 8 + b)) * 16384 + c * 128 + d0);
  const float qn = fmaxf(sqrtf(nq[b * 128 + c]), 1e-12f);
  const f32x2 nk2 = *(const f32x2*)(nk + b * 128 + d0);
  f32x2 sc;
  sc[0] = a[0] / (qn * fmaxf(sqrtf(nk2[0]), 1e-12f));
  sc[1] = a[1] / (qn * fmaxf(sqrtf(nk2[1]), 1e-12f));
  float mx = fmaxf(sc[0], sc[1]);
#pragma unroll
  for (int m = 32; m >= 1; m >>= 1) mx = fmaxf(mx, __shfl_xor(mx, m));
  f32x2 e; float sum;
  e[0] = __expf(sc[0] - mx); e[1] = __expf(sc[1] - mx);
  sum = e[0] + e[1];
#pragma unroll
  for (int m = 32; m >= 1; m >>= 1) sum += __shfl_xor(sum, m);
  const float inv = 1.f / sum;
  f32x2 o; o[0] = e[0] * inv; o[1] = e[1] * inv;
  *(f32x2*)(att + (size_t)b * 16384 + c * 128 + d0) = o;
}

// ---------------------------------------------------------------------------
// K4b: M[b][o][d] = sum_c out_w[o][c]*att[b][c][d], bf16.
//  grid 128 = b(8) x 16 d-groups of 8; att tile staged in LDS.
// ---------------------------------------------------------------------------
__global__ void k4b_mw(const float* __restrict__ att, const float* __restrict__ outw,
                       short* __restrict__ Mb)
{
  __shared__ float at[128][8];
  const int tid = threadIdx.x, bx = blockIdx.x;
  const int b = bx >> 4, d0 = (bx & 15) * 8;
  {
    const int cc = tid >> 1, q = tid & 1;
    *(f32x4*)&at[cc][q * 4] = *(const f32x4*)(att + (size_t)b * 16384 + cc * 128 + d0 + q * 4);
  }
  __syncthreads();
  const int o = tid & 127, dq = (tid >> 7) * 4;
  f32x4 acc = (f32x4){0.f, 0.f, 0.f, 0.f};
  const float* wr = outw + o * 128;
  for (int cc = 0; cc < 128; cc++) {
    const float w = wr[cc];
    const f32x4 a = *(const f32x4*)&at[cc][dq];
    acc += w * a;
  }
  s16x4 pk;
#pragma unroll
  for (int rg = 0; rg < 4; rg++) pk[rg] = f2bf(acc[rg]);
  *(s16x4*)(Mb + ((size_t)(b * 128 + o)) * 128 + d0 + dq) = pk;
}

// ---------------------------------------------------------------------------
// K5: out[b][n][o] = sum_d M[o][d]*v[d][n] + out_b[o] + cur[b][n][o].
//  v planar -> LDS transpose staging; D rows=o cols=pos; f32x4 stores.
//  grid 1024 = b(8) x 128 pos-chunks.
// ---------------------------------------------------------------------------
__global__ __launch_bounds__(256, 3)
void k5_out(const short* __restrict__ Mb, const short* __restrict__ vp,
            const float* __restrict__ outb, const float* __restrict__ cur,
            float* __restrict__ out)
{
  __shared__ __attribute__((aligned(16))) short Vt[128][136];
  const int tid = threadIdx.x;
  const int b = blockIdx.x >> 7, nb = (blockIdx.x & 127) * 128;
  {
    const int d = tid >> 1, hf = tid & 1;
    const short* src = vp + ((size_t)(b * 128 + d)) * 16384 + nb + hf * 64;
#pragma unroll
    for (int g = 0; g < 8; g++) {
      const s16x8 v = *(const s16x8*)(src + g * 8);
#pragma unroll
      for (int x = 0; x < 8; x++) Vt[hf * 64 + g * 8 + x][d] = v[x];
    }
  }
  __syncthreads();
  const int wv = tid >> 6, lane = tid & 63, l16 = lane & 15, quad = lane >> 4, kof = quad * 8;
  f32x4 acc[2][8];
#pragma unroll
  for (int i = 0; i < 2; i++)
#pragma unroll
    for (int j = 0; j < 8; j++) acc[i][j] = (f32x4){0.f, 0.f, 0.f, 0.f};

  const short* m0 = Mb + ((size_t)(b * 128 + wv * 32 + l16)) * 128;
  const short* m1 = m0 + 16 * 128;
#pragma unroll
  for (int ks = 0; ks < 4; ks++) {
    const int kb = ks * 32 + kof;
    const bf16x8 a0 = *(const bf16x8*)(m0 + kb);
    const bf16x8 a1 = *(const bf16x8*)(m1 + kb);
#pragma unroll
    for (int j = 0; j < 8; j++) {
      const bf16x8 bv = *(const bf16x8*)&Vt[j * 16 + l16][kb];
      acc[0][j] = __builtin_amdgcn_mfma_f32_16x16x32_bf16(a0, bv, acc[0][j], 0, 0, 0);
      acc[1][j] = __builtin_amdgcn_mfma_f32_16x16x32_bf16(a1, bv, acc[1][j], 0, 0, 0);
    }
  }
#pragma unroll
  for (int i = 0; i < 2; i++) {
    const int o0 = wv * 32 + i * 16 + quad * 4;
    const f32x4 bias = *(const f32x4*)(outb + o0);
#pragma unroll
    for (int j = 0; j < 8; j++) {
      const int pos = nb + j * 16 + l16;
      const size_t idx = ((size_t)(b * 16384 + pos)) * 128 + o0;
      const f32x4 cv = *(const f32x4*)(cur + idx);
      f32x4 rr;
#pragma unroll
      for (int rg = 0; rg < 4; rg++) rr[rg] = acc[i][j][rg] + bias[rg] + cv[rg];
      *(f32x4*)(out + idx) = rr;
    }
  }
}

// ---------------------------------------------------------------------------
extern "C" void kernel_launch(void* const* d_in, const int* in_sizes, int n_in,
                              void* d_out, int out_size, void* d_ws, size_t ws_size,
                              hipStream_t stream) {
  const float* pre  = (const float*)d_in[0];
  const float* cur  = (const float*)d_in[1];
  const float* ln1w = (const float*)d_in[2];
  const float* ln1b = (const float*)d_in[3];
  const float* ln2w = (const float*)d_in[4];
  const float* ln2b = (const float*)d_in[5];
  const float* qw1  = (const float*)d_in[6];
  const float* qb1  = (const float*)d_in[7];
  const float* qw2  = (const float*)d_in[8];
  const float* qb2  = (const float*)d_in[9];
  const float* kvw1 = (const float*)d_in[10];
  const float* kvb1 = (const float*)d_in[11];
  const float* kvw2 = (const float*)d_in[12];
  const float* kvb2 = (const float*)d_in[13];
  const float* outw = (const float*)d_in[14];
  const float* outb = (const float*)d_in[15];

  char* ws = (char*)d_ws;
  short* Yq  = (short*)(ws);                 // 32M planar [b*c][n]
  short* Yk  = (short*)(ws + 33554432);      // 32M planar
  short* Yv  = (short*)(ws + 67108864);      // 32M planar
  short* qo  = (short*)(ws + 100663296);     // 32M planar
  short* ko  = (short*)(ws + 134217728);     // 32M planar
  short* vo  = (short*)(ws + 167772160);     // 32M planar
  float* Gp  = (float*)(ws);                 // 32M, aliases Yq (dead after k2)
  float* att = (float*)(ws + 33554432);      // 512K, aliases Yk
  short* Mb  = (short*)(ws + 34078720);      // 256K, aliases Yk
  char*  sm  = ws + 201326592;
  short* Wq  = (short*)(sm);                 // 32K
  short* Wk  = (short*)(sm + 32768);
  short* Wv  = (short*)(sm + 65536);
  float* T   = (float*)(sm + 98304);         // 3K
  float* nq  = (float*)(sm + 102400);        // 4K
  float* nk  = (float*)(sm + 106496);        // 4K

  hipLaunchKernelGGL(k0_prep, dim3(3), dim3(256), 0, stream,
                     qw1, qb1, kvw1, kvb1, ln1w, ln1b, ln2w, ln2b, Wq, Wk, Wv, T);
  hipLaunchKernelGGL(k1_ln_gemm, dim3(1536), dim3(256), 0, stream,
                     cur, pre, Wq, Wk, Wv, T, Yq, Yk, Yv);
  hipLaunchKernelGGL(k2_plane, dim3(3072), dim3(256), 0, stream,
                     Yq, Yk, Yv, qw2, qb2, kvw2, kvb2, qo, ko, vo, nq, nk);
  hipLaunchKernelGGL(k3_gram, dim3(512), dim3(256), 0, stream, qo, ko, Gp);
  hipLaunchKernelGGL(k4a_softmax, dim3(256), dim3(256), 0, stream, Gp, nq, nk, att);
  hipLaunchKernelGGL(k4b_mw, dim3(128), dim3(256), 0, stream, att, outw, Mb);
  hipLaunchKernelGGL(k5_out, dim3(1024), dim3(256), 0, stream, Mb, vo, outb, cur, (float*)d_out);
}

// Round 5
// 386.506 us; speedup vs baseline: 1.2276x; 1.1029x over previous
//
#include <hip/hip_runtime.h>

// B=8, C=128, H=W=128, HW=16384, positions total P=131072
typedef __attribute__((ext_vector_type(4))) float f32x4;
typedef __attribute__((ext_vector_type(2))) float f32x2;
typedef __attribute__((ext_vector_type(8))) short s16x8;
typedef __attribute__((ext_vector_type(4))) short s16x4;
typedef __bf16 bf16x8 __attribute__((ext_vector_type(8)));

__device__ __forceinline__ short f2bf(float f) {
  union { float f; unsigned u; } c; c.f = f;
  unsigned r = c.u + 0x7fffu + ((c.u >> 16) & 1u);
  return (short)(r >> 16);
}
__device__ __forceinline__ float bf2f(short s) {
  union { unsigned u; float f; } c; c.u = ((unsigned)(unsigned short)s) << 16;
  return c.f;
}

// ---------------------------------------------------------------------------
// K0: prep. W'[o][c] = lw[c]*W[o][c] (bf16); t1[o]=sum_c W'[o][c];
//     t2[o]=sum_c lb[c]*W[o][c] + conv_bias[o].   grid 3 (q,k,v), block 256.
// ---------------------------------------------------------------------------
__global__ void k0_prep(const float* __restrict__ qw1, const float* __restrict__ qb1,
                        const float* __restrict__ kvw1, const float* __restrict__ kvb1,
                        const float* __restrict__ ln1w, const float* __restrict__ ln1b,
                        const float* __restrict__ ln2w, const float* __restrict__ ln2b,
                        short* __restrict__ Wq, short* __restrict__ Wk, short* __restrict__ Wv,
                        float* __restrict__ T)  // [6][128]: t1q,t2q,t1k,t2k,t1v,t2v
{
  const int path = blockIdx.x;
  const int o = threadIdx.x >> 1, hf = threadIdx.x & 1;
  const float *W, *bias, *lw, *lb; short* Wo; float *t1, *t2;
  if (path == 0)      { W = qw1;            bias = qb1;       lw = ln2w; lb = ln2b; Wo = Wq; t1 = T;       t2 = T + 128; }
  else if (path == 1) { W = kvw1;           bias = kvb1;      lw = ln1w; lb = ln1b; Wo = Wk; t1 = T + 256; t2 = T + 384; }
  else                { W = kvw1 + 16384;   bias = kvb1+128;  lw = ln1w; lb = ln1b; Wo = Wv; t1 = T + 512; t2 = T + 640; }
  float s1 = 0.f, s2 = 0.f;
  for (int g = 0; g < 64; g++) {
    const int c = hf * 64 + g;
    const float w = W[o * 128 + c];
    const float wp = w * lw[c];
    s1 += wp; s2 += w * lb[c];
    Wo[o * 128 + c] = f2bf(wp);
  }
  s1 += __shfl_xor(s1, 1);
  s2 += __shfl_xor(s2, 1);
  if (hf == 0) { t1[o] = s1; t2[o] = s2 + bias[o]; }
}

// ---------------------------------------------------------------------------
// K1: LN+1x1conv GEMM.  Round-0 proven structure (path-split grid 3072,
//  LDS A-tile, barrier-lockstep scatter epilogue = the ONLY store config
//  measured clean across r0-r4) + NEW: W' staged into LDS too.  Rationale:
//  r0's MFMA loop read B from global -> 64 dependent load->mfma pairs/wave
//  with ~200cy L2 latency exposed (~12.8K cyc/block, matching the measured
//  23.6K-cyc blocks vs ~10K HBM fair share).  Both operands now ds_read_b128
//  (compiler interleaves lgkmcnt finely).  LDS 73.7KB -> 2 blocks/CU, which
//  also SHRINKS the concurrent write-set vs r0 (cleaner, never dirtier).
// ---------------------------------------------------------------------------
__global__ __launch_bounds__(256, 2)
void k1_ln_gemm(const float* __restrict__ cur, const float* __restrict__ pre,
                const short* __restrict__ Wq, const short* __restrict__ Wk,
                const short* __restrict__ Wv, const float* __restrict__ T,
                short* __restrict__ Yq, short* __restrict__ Yk, short* __restrict__ Yv)
{
  __shared__ __attribute__((aligned(16))) short At[128][144];
  __shared__ __attribute__((aligned(16))) short Wl[128][144];
  __shared__ f32x2 rowstat[128];
  const int tid = threadIdx.x, bx = blockIdx.x;
  const int path = bx >> 10;
  const int mblk = bx & 1023;
  const float* X = (path == 0) ? cur : pre;
  const short* Wp = (path == 0) ? Wq : (path == 1) ? Wk : Wv;
  short* Yout = (path == 0) ? Yq : (path == 1) ? Yk : Yv;
  const float* t1 = T + path * 256;
  const float* t2 = t1 + 128;
  const int b = mblk >> 7;
  const int pl0 = (mblk & 127) * 128;

  // stage W' tile (32 KB, L2-hot: only 3 distinct tiles across the grid)
  {
    const int o = tid >> 1, hf = tid & 1;
    const short* src = Wp + o * 128 + hf * 64;
#pragma unroll
    for (int g = 0; g < 8; g++)
      *(s16x8*)&Wl[o][hf * 64 + g * 8] = *(const s16x8*)(src + g * 8);
  }
  // stage A-tile raw bf16 + row stats (identical to round-0)
  {
    const int r = tid >> 1, hf = tid & 1;
    const float* src = X + ((size_t)(mblk * 128 + r)) * 128 + hf * 64;
    float s1 = 0.f, s2 = 0.f;
#pragma unroll
    for (int g = 0; g < 8; g++) {
      const f32x4 v0 = *(const f32x4*)(src + g * 8);
      const f32x4 v1 = *(const f32x4*)(src + g * 8 + 4);
      s16x8 o;
#pragma unroll
      for (int j = 0; j < 4; j++) {
        s1 += v0[j] + v1[j]; s2 += v0[j] * v0[j] + v1[j] * v1[j];
        o[j] = f2bf(v0[j]); o[4 + j] = f2bf(v1[j]);
      }
      *(s16x8*)&At[r][hf * 64 + g * 8] = o;
    }
    s1 += __shfl_xor(s1, 1);
    s2 += __shfl_xor(s2, 1);
    if (hf == 0) {
      const float mu = s1 * (1.f / 128.f);
      const float var = s2 * (1.f / 128.f) - mu * mu;
      rowstat[r] = (f32x2){mu, rsqrtf(var + 1e-5f)};
    }
  }
  __syncthreads();

  const int wv = tid >> 6, lane = tid & 63, l16 = lane & 15, quad = lane >> 4, kof = quad * 8;
  f32x4 acc[2][8];
#pragma unroll
  for (int i = 0; i < 2; i++)
#pragma unroll
    for (int j = 0; j < 8; j++) acc[i][j] = (f32x4){0.f, 0.f, 0.f, 0.f};

#pragma unroll
  for (int ks = 0; ks < 4; ks++) {
    const int kb = ks * 32 + kof;
    const bf16x8 a0 = *(const bf16x8*)&At[wv * 32 + l16][kb];
    const bf16x8 a1 = *(const bf16x8*)&At[wv * 32 + 16 + l16][kb];
#pragma unroll
    for (int j = 0; j < 8; j++) {
      const bf16x8 bv = *(const bf16x8*)&Wl[j * 16 + l16][kb];
      acc[0][j] = __builtin_amdgcn_mfma_f32_16x16x32_bf16(a0, bv, acc[0][j], 0, 0, 0);
      acc[1][j] = __builtin_amdgcn_mfma_f32_16x16x32_bf16(a1, bv, acc[1][j], 0, 0, 0);
    }
  }

  float t1v[8], t2v[8];
#pragma unroll
  for (int j = 0; j < 8; j++) { const int o = j * 16 + l16; t1v[j] = t1[o]; t2v[j] = t2[o]; }
#pragma unroll
  for (int i = 0; i < 2; i++) {
    const int pr = wv * 32 + i * 16 + quad * 4;
    f32x2 st[4];
#pragma unroll
    for (int rg = 0; rg < 4; rg++) st[rg] = rowstat[pr + rg];
#pragma unroll
    for (int j = 0; j < 8; j++) {
      const int o = j * 16 + l16;
      s16x4 pk;
#pragma unroll
      for (int rg = 0; rg < 4; rg++) {
        const float y = st[rg].y * acc[i][j][rg] - st[rg].x * st[rg].y * t1v[j] + t2v[j];
        pk[rg] = f2bf(y);
      }
      *(s16x4*)(Yout + ((size_t)(b * 128 + o)) * 16384 + pl0 + pr) = pk;
    }
  }
}

// ---------------------------------------------------------------------------
// K2: depthwise 3x3 on planar [c-plane][128x128] bf16, vectorized sliding
//  window along w. grid 3072 = path(3) x b(8) x c(128); block 256 =
//  (row 128) x (w-half 2). Also per-plane sum-of-squares for q,k norms.
// ---------------------------------------------------------------------------
__global__ __launch_bounds__(256, 4)
void k2_plane(const short* __restrict__ Yq, const short* __restrict__ Yk,
              const short* __restrict__ Yv,
              const float* __restrict__ qw2, const float* __restrict__ qb2,
              const float* __restrict__ kvw2, const float* __restrict__ kvb2,
              short* __restrict__ qo, short* __restrict__ ko, short* __restrict__ vo,
              float* __restrict__ nq, float* __restrict__ nk)
{
  __shared__ __attribute__((aligned(16))) short tile[130][144]; // inner at [h+1][w+8]
  __shared__ float red[256];
  const int tid = threadIdx.x, bx = blockIdx.x;
  const int path = bx >> 10, rem = bx & 1023;
  const int b = rem >> 7, c = rem & 127;
  const short* in; const float* w2p; float bsv; short* outp; float* np;
  if (path == 0)      { in = Yq; w2p = qw2 + c * 9;          bsv = qb2[c];        outp = qo; np = nq; }
  else if (path == 1) { in = Yk; w2p = kvw2 + c * 9;         bsv = kvb2[c];       outp = ko; np = nk; }
  else                { in = Yv; w2p = kvw2 + (128 + c) * 9; bsv = kvb2[128 + c]; outp = vo; np = nullptr; }

  const short* plane = in + ((size_t)(b * 128 + c)) * 16384;
#pragma unroll
  for (int g = 0; g < 8; g++) {
    const int e = (g * 256 + tid) * 8;
    *(s16x8*)&tile[(e >> 7) + 1][(e & 127) + 8] = *(const s16x8*)(plane + e);
  }
  const s16x8 z8 = (s16x8){0, 0, 0, 0, 0, 0, 0, 0};
  if (tid < 128) *(s16x8*)&tile[tid + 1][136] = z8;          // right halo
  if (tid < 36) { const int rr = (tid / 18) * 129, cc = (tid % 18) * 8; *(s16x8*)&tile[rr][cc] = z8; }
  __syncthreads();

  float wt[9];
#pragma unroll
  for (int j = 0; j < 9; j++) wt[j] = w2p[j];
  const int rr = tid >> 1, hfc = tid & 1;

  float A0[8], A1[8], A2[8];
  {
    const int ca = 8 + hfc * 64;
    const s16x8 a0 = *(const s16x8*)&tile[rr][ca];
    const s16x8 a1 = *(const s16x8*)&tile[rr + 1][ca];
    const s16x8 a2 = *(const s16x8*)&tile[rr + 2][ca];
#pragma unroll
    for (int x = 0; x < 8; x++) { A0[x] = bf2f(a0[x]); A1[x] = bf2f(a1[x]); A2[x] = bf2f(a2[x]); }
  }
  float p0, p1, p2;
  if (hfc) { p0 = bf2f(tile[rr][71]); p1 = bf2f(tile[rr + 1][71]); p2 = bf2f(tile[rr + 2][71]); }
  else { p0 = p1 = p2 = 0.f; }

  float ss = 0.f;
  short* oplane = outp + ((size_t)(b * 128 + c)) * 16384 + rr * 128 + hfc * 64;
#pragma unroll
  for (int g = 0; g < 8; g++) {
    const int cb = 16 + hfc * 64 + g * 8;
    const s16x8 b0 = *(const s16x8*)&tile[rr][cb];
    const s16x8 b1 = *(const s16x8*)&tile[rr + 1][cb];
    const s16x8 b2 = *(const s16x8*)&tile[rr + 2][cb];
    float B0[8], B1[8], B2[8];
#pragma unroll
    for (int x = 0; x < 8; x++) { B0[x] = bf2f(b0[x]); B1[x] = bf2f(b1[x]); B2[x] = bf2f(b2[x]); }
    s16x8 ov;
#pragma unroll
    for (int x = 0; x < 8; x++) {
      const float l0 = x ? A0[x - 1] : p0, l1 = x ? A1[x - 1] : p1, l2 = x ? A2[x - 1] : p2;
      const float r0 = (x < 7) ? A0[x + 1] : B0[0];
      const float r1 = (x < 7) ? A1[x + 1] : B1[0];
      const float r2 = (x < 7) ? A2[x + 1] : B2[0];
      float s = bsv;
      s += wt[0] * l0 + wt[1] * A0[x] + wt[2] * r0;
      s += wt[3] * l1 + wt[4] * A1[x] + wt[5] * r1;
      s += wt[6] * l2 + wt[7] * A2[x] + wt[8] * r2;
      ov[x] = f2bf(s); ss += s * s;
    }
    *(s16x8*)(oplane + g * 8) = ov;
    p0 = A0[7]; p1 = A1[7]; p2 = A2[7];
#pragma unroll
    for (int x = 0; x < 8; x++) { A0[x] = B0[x]; A1[x] = B1[x]; A2[x] = B2[x]; }
  }
  red[tid] = ss;
  __syncthreads();
  if (tid < 64) {
    float t = red[tid] + red[tid + 64] + red[tid + 128] + red[tid + 192];
#pragma unroll
    for (int m = 32; m >= 1; m >>= 1) t += __shfl_xor(t, m);
    if (tid == 0 && np) np[b * 128 + c] = t;
  }
}

// ---------------------------------------------------------------------------
// K3: Gram partials from planar q,k — MFMA frags DIRECT from global.
//  grid 512 = b(8) x 64 n-splits of 256; block 256 computes full 128x128.
// ---------------------------------------------------------------------------
__global__ __launch_bounds__(256, 2)
void k3_gram(const short* __restrict__ qo, const short* __restrict__ ko,
             float* __restrict__ Gp)
{
  const int tid = threadIdx.x, bx = blockIdx.x;
  const int b = bx >> 6, sp = bx & 63;
  const int wv = tid >> 6, lane = tid & 63, l16 = lane & 15, quad = lane >> 4, kof = quad * 8;
  f32x4 acc[2][8];
#pragma unroll
  for (int i = 0; i < 2; i++)
#pragma unroll
    for (int j = 0; j < 8; j++) acc[i][j] = (f32x4){0.f, 0.f, 0.f, 0.f};

  const short* qb = qo + (size_t)b * 128 * 16384 + sp * 256 + kof;
  const short* kb = ko + (size_t)b * 128 * 16384 + sp * 256 + kof;
#pragma unroll
  for (int ks = 0; ks < 8; ks++) {
    const int n0 = ks * 32;
    const bf16x8 a0 = *(const bf16x8*)(qb + (size_t)(wv * 32 + l16) * 16384 + n0);
    const bf16x8 a1 = *(const bf16x8*)(qb + (size_t)(wv * 32 + 16 + l16) * 16384 + n0);
#pragma unroll
    for (int j = 0; j < 8; j++) {
      const bf16x8 bv = *(const bf16x8*)(kb + (size_t)(j * 16 + l16) * 16384 + n0);
      acc[0][j] = __builtin_amdgcn_mfma_f32_16x16x32_bf16(a0, bv, acc[0][j], 0, 0, 0);
      acc[1][j] = __builtin_amdgcn_mfma_f32_16x16x32_bf16(a1, bv, acc[1][j], 0, 0, 0);
    }
  }
  float* gp = Gp + ((size_t)(sp * 8 + b)) * 16384;
#pragma unroll
  for (int i = 0; i < 2; i++)
#pragma unroll
    for (int j = 0; j < 8; j++)
#pragma unroll
      for (int rg = 0; rg < 4; rg++)
        gp[(wv * 32 + i * 16 + quad * 4 + rg) * 128 + j * 16 + l16] = acc[i][j][rg];
}

// ---------------------------------------------------------------------------
// K4a: reduce 64 partials, l2-norm rescale, softmax over d.
//  One WAVE per attention row (b,c): lane d0 = lane*2, full 64-lane reduce.
//  grid 256 = b(8) x 32 c-quads; block 256 = 4 waves = 4 rows.
// ---------------------------------------------------------------------------
__global__ void k4a_softmax(const float* __restrict__ Gp,
                            const float* __restrict__ nq, const float* __restrict__ nk,
                            float* __restrict__ att)
{
  const int tid = threadIdx.x;
  const int b = blockIdx.x >> 5;
  const int c = (blockIdx.x & 31) * 4 + (tid >> 6);
  const int lane = tid & 63;
  const int d0 = lane * 2;
  f32x2 a = (f32x2){0.f, 0.f};
  for (int ks = 0; ks < 64; ks++)
    a += *(const f32x2*)(Gp + ((size_t)(ks * 8 + b)) * 16384 + c * 128 + d0);
  const float qn = fmaxf(sqrtf(nq[b * 128 + c]), 1e-12f);
  const f32x2 nk2 = *(const f32x2*)(nk + b * 128 + d0);
  f32x2 sc;
  sc[0] = a[0] / (qn * fmaxf(sqrtf(nk2[0]), 1e-12f));
  sc[1] = a[1] / (qn * fmaxf(sqrtf(nk2[1]), 1e-12f));
  float mx = fmaxf(sc[0], sc[1]);
#pragma unroll
  for (int m = 32; m >= 1; m >>= 1) mx = fmaxf(mx, __shfl_xor(mx, m));
  f32x2 e; float sum;
  e[0] = __expf(sc[0] - mx); e[1] = __expf(sc[1] - mx);
  sum = e[0] + e[1];
#pragma unroll
  for (int m = 32; m >= 1; m >>= 1) sum += __shfl_xor(sum, m);
  const float inv = 1.f / sum;
  f32x2 o; o[0] = e[0] * inv; o[1] = e[1] * inv;
  *(f32x2*)(att + (size_t)b * 16384 + c * 128 + d0) = o;
}

// ---------------------------------------------------------------------------
// K4b: M[b][o][d] = sum_c out_w[o][c]*att[b][c][d], bf16.
//  grid 128 = b(8) x 16 d-groups of 8; att tile staged in LDS.
// ---------------------------------------------------------------------------
__global__ void k4b_mw(const float* __restrict__ att, const float* __restrict__ outw,
                       short* __restrict__ Mb)
{
  __shared__ float at[128][8];
  const int tid = threadIdx.x, bx = blockIdx.x;
  const int b = bx >> 4, d0 = (bx & 15) * 8;
  {
    const int cc = tid >> 1, q = tid & 1;
    *(f32x4*)&at[cc][q * 4] = *(const f32x4*)(att + (size_t)b * 16384 + cc * 128 + d0 + q * 4);
  }
  __syncthreads();
  const int o = tid & 127, dq = (tid >> 7) * 4;
  f32x4 acc = (f32x4){0.f, 0.f, 0.f, 0.f};
  const float* wr = outw + o * 128;
  for (int cc = 0; cc < 128; cc++) {
    const float w = wr[cc];
    const f32x4 a = *(const f32x4*)&at[cc][dq];
    acc += w * a;
  }
  s16x4 pk;
#pragma unroll
  for (int rg = 0; rg < 4; rg++) pk[rg] = f2bf(acc[rg]);
  *(s16x4*)(Mb + ((size_t)(b * 128 + o)) * 128 + d0 + dq) = pk;
}

// ---------------------------------------------------------------------------
// K5: out[b][n][o] = sum_d M[o][d]*v[d][n] + out_b[o] + cur[b][n][o].
//  v planar -> LDS transpose staging; D rows=o cols=pos; f32x4 stores.
//  grid 1024 = b(8) x 128 pos-chunks.
// ---------------------------------------------------------------------------
__global__ __launch_bounds__(256, 3)
void k5_out(const short* __restrict__ Mb, const short* __restrict__ vp,
            const float* __restrict__ outb, const float* __restrict__ cur,
            float* __restrict__ out)
{
  __shared__ __attribute__((aligned(16))) short Vt[128][136];
  const int tid = threadIdx.x;
  const int b = blockIdx.x >> 7, nb = (blockIdx.x & 127) * 128;
  {
    const int d = tid >> 1, hf = tid & 1;
    const short* src = vp + ((size_t)(b * 128 + d)) * 16384 + nb + hf * 64;
#pragma unroll
    for (int g = 0; g < 8; g++) {
      const s16x8 v = *(const s16x8*)(src + g * 8);
#pragma unroll
      for (int x = 0; x < 8; x++) Vt[hf * 64 + g * 8 + x][d] = v[x];
    }
  }
  __syncthreads();
  const int wv = tid >> 6, lane = tid & 63, l16 = lane & 15, quad = lane >> 4, kof = quad * 8;
  f32x4 acc[2][8];
#pragma unroll
  for (int i = 0; i < 2; i++)
#pragma unroll
    for (int j = 0; j < 8; j++) acc[i][j] = (f32x4){0.f, 0.f, 0.f, 0.f};

  const short* m0 = Mb + ((size_t)(b * 128 + wv * 32 + l16)) * 128;
  const short* m1 = m0 + 16 * 128;
#pragma unroll
  for (int ks = 0; ks < 4; ks++) {
    const int kb = ks * 32 + kof;
    const bf16x8 a0 = *(const bf16x8*)(m0 + kb);
    const bf16x8 a1 = *(const bf16x8*)(m1 + kb);
#pragma unroll
    for (int j = 0; j < 8; j++) {
      const bf16x8 bv = *(const bf16x8*)&Vt[j * 16 + l16][kb];
      acc[0][j] = __builtin_amdgcn_mfma_f32_16x16x32_bf16(a0, bv, acc[0][j], 0, 0, 0);
      acc[1][j] = __builtin_amdgcn_mfma_f32_16x16x32_bf16(a1, bv, acc[1][j], 0, 0, 0);
    }
  }
#pragma unroll
  for (int i = 0; i < 2; i++) {
    const int o0 = wv * 32 + i * 16 + quad * 4;
    const f32x4 bias = *(const f32x4*)(outb + o0);
#pragma unroll
    for (int j = 0; j < 8; j++) {
      const int pos = nb + j * 16 + l16;
      const size_t idx = ((size_t)(b * 16384 + pos)) * 128 + o0;
      const f32x4 cv = *(const f32x4*)(cur + idx);
      f32x4 rr;
#pragma unroll
      for (int rg = 0; rg < 4; rg++) rr[rg] = acc[i][j][rg] + bias[rg] + cv[rg];
      *(f32x4*)(out + idx) = rr;
    }
  }
}

// ---------------------------------------------------------------------------
extern "C" void kernel_launch(void* const* d_in, const int* in_sizes, int n_in,
                              void* d_out, int out_size, void* d_ws, size_t ws_size,
                              hipStream_t stream) {
  const float* pre  = (const float*)d_in[0];
  const float* cur  = (const float*)d_in[1];
  const float* ln1w = (const float*)d_in[2];
  const float* ln1b = (const float*)d_in[3];
  const float* ln2w = (const float*)d_in[4];
  const float* ln2b = (const float*)d_in[5];
  const float* qw1  = (const float*)d_in[6];
  const float* qb1  = (const float*)d_in[7];
  const float* qw2  = (const float*)d_in[8];
  const float* qb2  = (const float*)d_in[9];
  const float* kvw1 = (const float*)d_in[10];
  const float* kvb1 = (const float*)d_in[11];
  const float* kvw2 = (const float*)d_in[12];
  const float* kvb2 = (const float*)d_in[13];
  const float* outw = (const float*)d_in[14];
  const float* outb = (const float*)d_in[15];

  char* ws = (char*)d_ws;
  short* Yq  = (short*)(ws);                 // 32M planar [b*c][n]
  short* Yk  = (short*)(ws + 33554432);      // 32M planar
  short* Yv  = (short*)(ws + 67108864);      // 32M planar
  short* qo  = (short*)(ws + 100663296);     // 32M planar
  short* ko  = (short*)(ws + 134217728);     // 32M planar
  short* vo  = (short*)(ws + 167772160);     // 32M planar
  float* Gp  = (float*)(ws);                 // 32M, aliases Yq (dead after k2)
  float* att = (float*)(ws + 33554432);      // 512K, aliases Yk
  short* Mb  = (short*)(ws + 34078720);      // 256K, aliases Yk
  char*  sm  = ws + 201326592;
  short* Wq  = (short*)(sm);                 // 32K
  short* Wk  = (short*)(sm + 32768);
  short* Wv  = (short*)(sm + 65536);
  float* T   = (float*)(sm + 98304);         // 3K
  float* nq  = (float*)(sm + 102400);        // 4K
  float* nk  = (float*)(sm + 106496);        // 4K

  hipLaunchKernelGGL(k0_prep, dim3(3), dim3(256), 0, stream,
                     qw1, qb1, kvw1, kvb1, ln1w, ln1b, ln2w, ln2b, Wq, Wk, Wv, T);
  hipLaunchKernelGGL(k1_ln_gemm, dim3(3072), dim3(256), 0, stream,
                     cur, pre, Wq, Wk, Wv, T, Yq, Yk, Yv);
  hipLaunchKernelGGL(k2_plane, dim3(3072), dim3(256), 0, stream,
                     Yq, Yk, Yv, qw2, qb2, kvw2, kvb2, qo, ko, vo, nq, nk);
  hipLaunchKernelGGL(k3_gram, dim3(512), dim3(256), 0, stream, qo, ko, Gp);
  hipLaunchKernelGGL(k4a_softmax, dim3(256), dim3(256), 0, stream, Gp, nq, nk, att);
  hipLaunchKernelGGL(k4b_mw, dim3(128), dim3(256), 0, stream, att, outw, Mb);
  hipLaunchKernelGGL(k5_out, dim3(1024), dim3(256), 0, stream, Mb, vo, outb, cur, (float*)d_out);
}